// Round 3
// baseline (361.020 us; speedup 1.0000x reference)
//
#include <hip/hip_runtime.h>
#include <hip/hip_bf16.h>
#include <stdint.h>

// DequantingLinear: out[TOK,OUT] = x[TOK,IN] @ dequant(w_q,w_scales)^T + bias
// R3: full 8-phase 256x256 BK=64 schedule (T2 swizzle + T3/T4 counted vmcnt +
// T5 setprio). Each phase: 12 ds_read_b128 + 1 half-tile stage (2 gload_lds)
// -> barrier -> 16 MFMA -> barrier. vmcnt(2) before trailing barriers of
// phases 3 and 7 only (never 0 in steady state).

typedef __bf16 bf16;
typedef __bf16 bf16x8 __attribute__((ext_vector_type(8)));
typedef float f32x4 __attribute__((ext_vector_type(4)));

#define AS1 __attribute__((address_space(1)))
#define AS3 __attribute__((address_space(3)))

__device__ __forceinline__ void gload_lds16(const void* g, void* l) {
    __builtin_amdgcn_global_load_lds((AS1 void*)g, (AS3 void*)l, 16, 0, 0);
}

#define MFMA16(d, x, y) d = __builtin_amdgcn_mfma_f32_16x16x32_bf16(x, y, d, 0, 0, 0)

// ---------------- Pass 1a: dequantize w_q (int32) * scale -> bf16 ----------
__global__ __launch_bounds__(128) void k_dequant(
    const int* __restrict__ q, const float* __restrict__ sc,
    bf16* __restrict__ w, int IN) {
    const int row = blockIdx.y;
    const int k = (blockIdx.x * 128 + threadIdx.x) * 8;
    if (k >= IN) return;
    const float s = sc[(size_t)row * (IN >> 5) + (k >> 5)];
    const size_t base = (size_t)row * IN + k;
    const int4 q0 = *(const int4*)(q + base);
    const int4 q1 = *(const int4*)(q + base + 4);
    bf16x8 o;
    o[0] = (bf16)(q0.x * s); o[1] = (bf16)(q0.y * s);
    o[2] = (bf16)(q0.z * s); o[3] = (bf16)(q0.w * s);
    o[4] = (bf16)(q1.x * s); o[5] = (bf16)(q1.y * s);
    o[6] = (bf16)(q1.z * s); o[7] = (bf16)(q1.w * s);
    *(bf16x8*)(w + base) = o;
}

// ---------------- Pass 1b: x f32 -> bf16 -----------------------------------
__global__ __launch_bounds__(256) void k_cvt(
    const float* __restrict__ x, bf16* __restrict__ xb, long long n8) {
    long long i = (long long)blockIdx.x * 256 + threadIdx.x;
    const long long stride = (long long)gridDim.x * 256;
    for (; i < n8; i += stride) {
        const float4 a = *(const float4*)(x + i * 8);
        const float4 b = *(const float4*)(x + i * 8 + 4);
        bf16x8 o;
        o[0] = (bf16)a.x; o[1] = (bf16)a.y; o[2] = (bf16)a.z; o[3] = (bf16)a.w;
        o[4] = (bf16)b.x; o[5] = (bf16)b.y; o[6] = (bf16)b.z; o[7] = (bf16)b.w;
        *(bf16x8*)(xb + i * 8) = o;
    }
}

// ---------------- Pass 2: 256x256 bf16 GEMM, 8-phase schedule --------------
// A:[M][K] (x), B:[N][K] (W'), C:[M][N] f32.  512 thr = 8 waves (2M x 4N);
// wave out 128x64; phase = one 64x32 C-quadrant over K=64 (16 MFMA).
// LDS buf{0,1} @ {0,65536}; in buf: A @0 (rows 256 x 128B), B @32768.
// Half-tiles: AL rows0-127, AH rows128-255 (16KB each); same for B.
// Swizzle: LDS(row,cb) holds logical col cb ^ ((row&7)<<4); staged via
// pre-swizzled global source + linear gload_lds dest (rule 21).
__global__ __launch_bounds__(512, 2) void k_gemm8p(
    const bf16* __restrict__ A, const bf16* __restrict__ B,
    const float* __restrict__ bias, float* __restrict__ C,
    int M, int N, int K) {
    __shared__ __align__(16) char lds[131072];
    const int tid = threadIdx.x;
    const int wv = tid >> 6, ln = tid & 63;
    const int wm = wv >> 2, wn = wv & 3;
    const int nbn = N >> 8;
    const int nwg = gridDim.x;
    const int q8 = nwg >> 3, r8 = nwg & 7;
    const int xcd = blockIdx.x & 7, lin = blockIdx.x >> 3;
    const int swz = (xcd < r8 ? xcd * (q8 + 1)
                              : r8 * (q8 + 1) + (xcd - r8) * q8) + lin;
    const int bm = swz / nbn, bn = swz % nbn;

    // staging source (pre-swizzled): thread covers row (tid>>3)+{0,64} per
    // gload, colbyte ((tid&7)^(row&7))*16
    const size_t rowb = (size_t)K * 2;
    const int scol = (((tid ^ (tid >> 3)) & 7) << 4);
    const char* Ag = (const char*)A + ((size_t)(bm << 8) + (tid >> 3)) * rowb + scol;
    const char* Bg = (const char*)B + ((size_t)(bn << 8) + (tid >> 3)) * rowb + scol;
    const char* Ag128 = Ag + (size_t)128 * rowb;
    const char* Bg128 = Bg + (size_t)128 * rowb;
    const int ldsw = wv << 10;

    // one half-tile = 2 gload_lds (rows +0..63 and +64..127 of the half)
#define STG(dst_, src_, kt_) do {                                             \
        const size_t kb_ = (size_t)(kt_) << 1;                                \
        gload_lds16((src_) + kb_, lds + (dst_) + ldsw);                       \
        gload_lds16((src_) + (size_t)64 * rowb + kb_,                         \
                    lds + (dst_) + 8192 + ldsw);                              \
    } while (0)

    // ds_read swizzled column bytes for kslice 0/1
    const int colx = ((ln & 4) << 4) | ((((ln >> 4) ^ ln) & 3) << 4);
    const int c0 = colx, c1 = colx ^ 64;
    const int abase = (((wm << 7) + (ln & 15)) << 7);
    const int bbase = (((wn << 6) + (ln & 15)) << 7);

    f32x4 acc[8][4] = {};

#define SB __builtin_amdgcn_sched_barrier(0)
#define BAR __builtin_amdgcn_s_barrier()
#define VMW2 asm volatile("s_waitcnt vmcnt(2)" ::: "memory")
#define VMW0 asm volatile("s_waitcnt vmcnt(0)" ::: "memory")

    // phase: quadrant (h_,c_) of tile in buf cb_; STAGE issued pre-barrier;
    // ENDW (vmcnt wait) before trailing barrier so all waves' staged loads
    // are landed after it.
#define PHASE(cb_, h_, c_, STAGE_STMT, ENDW_STMT) do {                        \
        const char* bA_ = lds + (cb_);                                        \
        const char* bB_ = lds + (cb_) + 32768;                                \
        bf16x8 paf[8], pbf[4];                                                \
        _Pragma("unroll")                                                     \
        for (int r = 0; r < 4; ++r) {                                         \
            paf[r*2+0] = *(const bf16x8*)(bA_ + abase + (h_)*8192 + (r<<11) + c0); \
            paf[r*2+1] = *(const bf16x8*)(bA_ + abase + (h_)*8192 + (r<<11) + c1); \
        }                                                                     \
        _Pragma("unroll")                                                     \
        for (int rb = 0; rb < 2; ++rb) {                                      \
            pbf[rb*2+0] = *(const bf16x8*)(bB_ + bbase + (((c_)*2+rb)<<11) + c0); \
            pbf[rb*2+1] = *(const bf16x8*)(bB_ + bbase + (((c_)*2+rb)<<11) + c1); \
        }                                                                     \
        STAGE_STMT;                                                           \
        SB; BAR; SB;                                                          \
        __builtin_amdgcn_s_setprio(1);                                        \
        _Pragma("unroll")                                                     \
        for (int r = 0; r < 4; ++r)                                           \
            _Pragma("unroll")                                                 \
            for (int rb = 0; rb < 2; ++rb) {                                  \
                MFMA16(acc[(h_)*4+r][(c_)*2+rb], paf[r*2+0], pbf[rb*2+0]);    \
                MFMA16(acc[(h_)*4+r][(c_)*2+rb], paf[r*2+1], pbf[rb*2+1]);    \
            }                                                                 \
        __builtin_amdgcn_s_setprio(0);                                        \
        ENDW_STMT;                                                            \
        SB; BAR; SB;                                                          \
    } while (0)

    // ---- prologue: tile0 (buf0) all 4 halves + tile1 AL; leave (1,AL) in flight
    STG(0,      Ag,    0);   // (0,AL)
    STG(16384,  Ag128, 0);   // (0,AH)
    STG(32768,  Bg,    0);   // (0,BL)
    STG(49152,  Bg128, 0);   // (0,BH)
    STG(65536,  Ag,    64);  // (1,AL)
    VMW2;
    SB; BAR; SB;

    const int NITER = K >> 7;  // pairs of K-tiles
    for (int j = 0; j < NITER - 1; ++j) {
        const int kt1 = (j << 7) + 64, kt2 = kt1 + 64, kt3 = kt2 + 64;
        PHASE(0,     0, 0, STG(81920,  Ag128, kt1), (void)0);  // stage (T1,AH)
        PHASE(0,     0, 1, STG(98304,  Bg,    kt1), (void)0);  // (T1,BL)
        PHASE(0,     1, 0, STG(114688, Bg128, kt1), (void)0);  // (T1,BH)
        PHASE(0,     1, 1, STG(0,      Ag,    kt2), VMW2);     // (T2,AL) + W1
        PHASE(65536, 0, 0, STG(16384,  Ag128, kt2), (void)0);  // (T2,AH)
        PHASE(65536, 0, 1, STG(32768,  Bg,    kt2), (void)0);  // (T2,BL)
        PHASE(65536, 1, 0, STG(49152,  Bg128, kt2), (void)0);  // (T2,BH)
        PHASE(65536, 1, 1, STG(65536,  Ag,    kt3), VMW2);     // (T3,AL) + W2
    }
    {   // peeled last iteration: stage only (T1,AH/BL/BH); drain at ph3
        const int kt1 = ((NITER - 1) << 7) + 64;
        PHASE(0,     0, 0, STG(81920,  Ag128, kt1), (void)0);
        PHASE(0,     0, 1, STG(98304,  Bg,    kt1), (void)0);
        PHASE(0,     1, 0, STG(114688, Bg128, kt1), (void)0);
        PHASE(0,     1, 1, (void)0,                 VMW0);
        PHASE(65536, 0, 0, (void)0, (void)0);
        PHASE(65536, 0, 1, (void)0, (void)0);
        PHASE(65536, 1, 0, (void)0, (void)0);
        PHASE(65536, 1, 1, (void)0, (void)0);
    }
#undef PHASE
#undef STG

    // ---- epilogue: D layout col=lane&15, row=(lane>>4)*4+reg
    const int erow = (bm << 8) + (wm << 7) + ((ln >> 4) << 2);
    const int ecol = (bn << 8) + (wn << 6) + (ln & 15);
    float bv[4];
#pragma unroll
    for (int n = 0; n < 4; ++n) bv[n] = bias[ecol + (n << 4)];
#pragma unroll
    for (int m = 0; m < 8; ++m)
#pragma unroll
        for (int r = 0; r < 4; ++r) {
            float* Crow = C + (size_t)(erow + (m << 4) + r) * N + ecol;
#pragma unroll
            for (int n = 0; n < 4; ++n)
                Crow[n << 4] = acc[m][n][r] + bv[n];
        }
}

// ---------------- Fallback: fused dequant+GEMM (no workspace) --------------
__global__ __launch_bounds__(256) void k_fused(
    const float* __restrict__ X, const int* __restrict__ Q,
    const float* __restrict__ SC, const float* __restrict__ bias,
    float* __restrict__ C, int M, int N, int K) {
    __shared__ __align__(16) bf16 sA[128 * 32];
    __shared__ __align__(16) bf16 sB[128 * 32];
    const int tid = threadIdx.x;
    const int wv = tid >> 6;
    const int ln = tid & 63;
    const int nbn = N >> 7;
    const int nwg = gridDim.x;
    const int q8 = nwg >> 3, r8 = nwg & 7;
    const int xcd = blockIdx.x & 7, lin = blockIdx.x >> 3;
    const int swz = (xcd < r8 ? xcd * (q8 + 1)
                              : r8 * (q8 + 1) + (xcd - r8) * q8) + lin;
    const int bm = swz / nbn, bn = swz % nbn;
    const int wr = (wv >> 1) << 6;
    const int wc = (wv & 1) << 6;
    const int srow = tid >> 1;
    const int sk = (tid & 1) << 4;

    f32x4 acc[4][4] = {};
    const float* xrow = X + (size_t)((bm << 7) + srow) * K + sk;
    const int* qrow = Q + (size_t)((bn << 7) + srow) * K + sk;
    const float* scrow = SC + (size_t)((bn << 7) + srow) * (K >> 5);

    for (int kt = 0; kt < K; kt += 32) {
        const float4 a0 = *(const float4*)(xrow + kt);
        const float4 a1 = *(const float4*)(xrow + kt + 4);
        const float4 a2 = *(const float4*)(xrow + kt + 8);
        const float4 a3 = *(const float4*)(xrow + kt + 12);
        const int4 q0 = *(const int4*)(qrow + kt);
        const int4 q1 = *(const int4*)(qrow + kt + 4);
        const int4 q2 = *(const int4*)(qrow + kt + 8);
        const int4 q3 = *(const int4*)(qrow + kt + 12);
        const float s = scrow[(kt + sk) >> 5];
        bf16x8 wa0, wa1, wb0, wb1;
        wa0[0] = (bf16)a0.x; wa0[1] = (bf16)a0.y; wa0[2] = (bf16)a0.z; wa0[3] = (bf16)a0.w;
        wa0[4] = (bf16)a1.x; wa0[5] = (bf16)a1.y; wa0[6] = (bf16)a1.z; wa0[7] = (bf16)a1.w;
        wa1[0] = (bf16)a2.x; wa1[1] = (bf16)a2.y; wa1[2] = (bf16)a2.z; wa1[3] = (bf16)a2.w;
        wa1[4] = (bf16)a3.x; wa1[5] = (bf16)a3.y; wa1[6] = (bf16)a3.z; wa1[7] = (bf16)a3.w;
        wb0[0] = (bf16)(q0.x * s); wb0[1] = (bf16)(q0.y * s);
        wb0[2] = (bf16)(q0.z * s); wb0[3] = (bf16)(q0.w * s);
        wb0[4] = (bf16)(q1.x * s); wb0[5] = (bf16)(q1.y * s);
        wb0[6] = (bf16)(q1.z * s); wb0[7] = (bf16)(q1.w * s);
        wb1[0] = (bf16)(q2.x * s); wb1[1] = (bf16)(q2.y * s);
        wb1[2] = (bf16)(q2.z * s); wb1[3] = (bf16)(q2.w * s);
        wb1[4] = (bf16)(q3.x * s); wb1[5] = (bf16)(q3.y * s);
        wb1[6] = (bf16)(q3.z * s); wb1[7] = (bf16)(q3.w * s);
        __syncthreads();
        *(bf16x8*)(sA + srow * 32 + sk) = wa0;
        *(bf16x8*)(sA + srow * 32 + sk + 8) = wa1;
        *(bf16x8*)(sB + srow * 32 + sk) = wb0;
        *(bf16x8*)(sB + srow * 32 + sk + 8) = wb1;
        __syncthreads();

        bf16x8 af[4], bg[4];
#pragma unroll
        for (int m = 0; m < 4; ++m)
            af[m] = *(const bf16x8*)(sA + ((wr + (m << 4) + (ln & 15)) << 5) +
                                     ((ln >> 4) << 3));
#pragma unroll
        for (int n = 0; n < 4; ++n)
            bg[n] = *(const bf16x8*)(sB + ((wc + (n << 4) + (ln & 15)) << 5) +
                                     ((ln >> 4) << 3));
#pragma unroll
        for (int m = 0; m < 4; ++m)
#pragma unroll
            for (int n = 0; n < 4; ++n)
                acc[m][n] = __builtin_amdgcn_mfma_f32_16x16x32_bf16(
                    af[m], bg[n], acc[m][n], 0, 0, 0);
    }

    float bv[4];
#pragma unroll
    for (int n = 0; n < 4; ++n)
        bv[n] = bias[(bn << 7) + wc + (n << 4) + (ln & 15)];
#pragma unroll
    for (int m = 0; m < 4; ++m) {
        const int grow0 = (bm << 7) + wr + (m << 4) + ((ln >> 4) << 2);
#pragma unroll
        for (int r = 0; r < 4; ++r) {
            float* Crow = C + (size_t)(grow0 + r) * N;
#pragma unroll
            for (int n = 0; n < 4; ++n)
                Crow[(bn << 7) + wc + (n << 4) + (ln & 15)] =
                    acc[m][n][r] + bv[n];
        }
    }
}

extern "C" void kernel_launch(void* const* d_in, const int* in_sizes, int n_in,
                              void* d_out, int out_size, void* d_ws, size_t ws_size,
                              hipStream_t stream) {
    const float* x = (const float*)d_in[0];
    const int* wq = (const int*)d_in[1];
    const float* sc = (const float*)d_in[2];
    const float* bias = (const float*)d_in[3];
    float* out = (float*)d_out;

    const long long xN = in_sizes[0];  // TOK*IN
    const long long wN = in_sizes[1];  // OUT*IN
    const int OUT = in_sizes[3];       // bias length
    const int IN = (int)(wN / OUT);
    const int TOK = (int)(xN / IN);
    const int M = TOK, N = OUT, K = IN;

    const size_t wb_bytes = (size_t)wN * 2;
    const size_t xb_bytes = (size_t)xN * 2;
    const bool ok8p = (M % 256 == 0) && (N % 256 == 0) && (K % 128 == 0) &&
                      (K >= 256);

    if (ok8p && ws_size >= wb_bytes + xb_bytes) {
        bf16* Wb = (bf16*)d_ws;
        bf16* Xb = (bf16*)((char*)d_ws + wb_bytes);
        dim3 dq_grid((IN / 8 + 127) / 128, OUT);
        k_dequant<<<dq_grid, 128, 0, stream>>>(wq, sc, Wb, IN);
        const long long n8 = xN / 8;
        int cvt_blocks = (int)((n8 + 255) / 256);
        if (cvt_blocks > 2048) cvt_blocks = 2048;
        k_cvt<<<cvt_blocks, 256, 0, stream>>>(x, Xb, n8);
        const int grid = (M / 256) * (N / 256);
        k_gemm8p<<<grid, 512, 0, stream>>>(Xb, Wb, bias, out, M, N, K);
    } else {
        const int grid = (M / 128) * (N / 128);
        k_fused<<<grid, 256, 0, stream>>>(x, wq, sc, bias, out, M, N, K);
    }
}